// Round 8
// baseline (2191.340 us; speedup 1.0000x reference)
//
#include <hip/hip_runtime.h>

#define NN 10000      // nodes

typedef __attribute__((ext_vector_type(8))) short short8;
typedef __attribute__((ext_vector_type(4))) float f32x4;

__device__ __forceinline__ ushort f2b(float f) {
    union { float f; uint32_t u; } v; v.f = f;
    uint32_t u = v.u;
    return (ushort)((u + 0x7fffu + ((u >> 16) & 1u)) >> 16);
}
__device__ __forceinline__ uint packbf(float a, float b) {
    return (uint)f2b(a) | ((uint)f2b(b) << 16);
}
__device__ __forceinline__ float blo(uint u) {
    union { uint u; float f; } v; v.u = u << 16; return v.f;
}
__device__ __forceinline__ float bhi(uint u) {
    union { uint u; float f; } v; v.u = u & 0xffff0000u; return v.f;
}

// ---------------------------------------------------------------------------
// CSR build kernels (proven)
// ---------------------------------------------------------------------------
__global__ __launch_bounds__(1024) void scan_build(const int* __restrict__ counts,
                                                   int* __restrict__ offsets,
                                                   int* __restrict__ cursor,
                                                   float* __restrict__ inv_cnt, int n) {
    __shared__ int part[1024];
    int tid = threadIdx.x;
    int per = (n + 1023) / 1024;
    int base = tid * per;
    int s = 0;
    for (int i = 0; i < per; i++) { int idx = base + i; if (idx < n) s += counts[idx]; }
    part[tid] = s;
    __syncthreads();
    for (int off = 1; off < 1024; off <<= 1) {
        int v = (tid >= off) ? part[tid - off] : 0;
        __syncthreads();
        part[tid] += v;
        __syncthreads();
    }
    int run = (tid > 0) ? part[tid - 1] : 0;
    for (int i = 0; i < per; i++) {
        int idx = base + i;
        if (idx < n) {
            int c = counts[idx];
            offsets[idx] = run;
            cursor[idx]  = run;
            inv_cnt[idx] = 1.0f / fmaxf((float)c, 1.0f);
            run += c;
        }
    }
}

__global__ __launch_bounds__(256) void scatter_edges(const int* __restrict__ src,
                                                     const int* __restrict__ dst,
                                                     int* __restrict__ cursor,
                                                     int* __restrict__ sorted_src, int E) {
    int i = blockIdx.x * 256 + threadIdx.x;
    if (i < E) {
        int p = atomicAdd(&cursor[dst[i]], 1);
        sorted_src[p] = src[i];
    }
}

// ---------------------------------------------------------------------------
// cvt_x: fp32 x -> bf16 xcat right half. Also zeroes counts + flag arrays.
// xcat row layout: [0:512) = xagg (bf16), [512:1024) = x (bf16).
// ---------------------------------------------------------------------------
__global__ __launch_bounds__(256) void cvt_x(const float* __restrict__ in,
                                             ushort* __restrict__ xcat,
                                             int* __restrict__ counts,
                                             int* __restrict__ flagbase, int n4) {
    int i = blockIdx.x * 256 + threadIdx.x;
    if (i < NN) counts[i] = 0;
    if (i < 968) flagbase[i] = 0;     // 3 queues + 3x157 aggdone + 3x157 gemmdone
    if (i >= n4) return;
    int idx = i * 4;
    int node = idx >> 9;         // din = 512
    int col  = idx & 511;
    float4 v = *(const float4*)(in + (size_t)node * 512 + col);
    uint2 p;
    p.x = packbf(v.x, v.y);
    p.y = packbf(v.z, v.w);
    *(uint2*)(xcat + (size_t)node * 1024 + 512 + col) = p;
}

// All three weight sets -> one bf16 buffer. Also does count_dst (i < E).
// Wcat rows: [0,512) layer0, [512,1024) layer1, [1024,1280) layer2;
// each row 1024 wide: [0:512)=Wl[r], [512:1024)=Wr[r].
__global__ __launch_bounds__(256) void cvt_w_all(const float* __restrict__ Wl0,
                                                 const float* __restrict__ Wr0,
                                                 const float* __restrict__ Wl1,
                                                 const float* __restrict__ Wr1,
                                                 const float* __restrict__ Wl2,
                                                 const float* __restrict__ Wr2,
                                                 ushort* __restrict__ out,
                                                 const int* __restrict__ dst,
                                                 int* __restrict__ counts,
                                                 int E, int n4) {
    int i = blockIdx.x * 256 + threadIdx.x;
    if (i < E) atomicAdd(&counts[dst[i]], 1);
    if (i >= n4) return;
    int idx = i * 4;
    int row = idx >> 10;
    int col = idx & 1023;
    const float* Wl; const float* Wr; int r;
    if (row < 512)       { Wl = Wl0; Wr = Wr0; r = row; }
    else if (row < 1024) { Wl = Wl1; Wr = Wr1; r = row - 512; }
    else                 { Wl = Wl2; Wr = Wr2; r = row - 1024; }
    const float* src = (col < 512) ? (Wl + (size_t)r * 512 + col)
                                   : (Wr + (size_t)r * 512 + col - 512);
    float4 v = *(const float4*)src;
    uint2 p;
    p.x = packbf(v.x, v.y);
    p.y = packbf(v.z, v.w);
    *(uint2*)(out + idx) = p;
}

// ---------------------------------------------------------------------------
// Fused persistent layer kernel. Work queue (single atomic counter):
//   items [0, NAGG)           : agg item  = 4 nodes (R4 agg_mean body)
//   items [NAGG, NAGG+NGEMM)  : gemm tile = 64x128 (R4 gemm_mfma body)
//   items [.., TOTAL)         : finalize  = 4 nodes (R4 finalize body)
// Deps: gemm tile (bm,bn) waits aggdone[bm]; finalize waits gemmdone[bm].
// Producer: stores -> __threadfence -> __syncthreads -> t0 flag atomicAdd.
// Consumer: t0 polls flag (device RMW) -> __syncthreads -> all __threadfence.
// Deadlock-free for any grid: queue order == dependency order, so the
// globally-earliest unfinished item always has satisfied deps and a block.
// ---------------------------------------------------------------------------
template <int NTILE, bool FINAL>
__global__ __launch_bounds__(256) void layer_fused(
        ushort* __restrict__ xcat,
        const ushort* __restrict__ B,
        const float* __restrict__ bias,
        float* __restrict__ Cbuf,
        const int* __restrict__ offsets,
        const int* __restrict__ counts,
        const int* __restrict__ sorted_src,
        const float* __restrict__ inv_cnt,
        int* __restrict__ queue,
        int* __restrict__ aggdone,
        int* __restrict__ gemmdone,
        float* __restrict__ outf,
        int n)
{
    constexpr int Nn    = NTILE * 128;       // 512 or 256
    constexpr int NAGG  = (NN + 3) / 4;      // 2500
    constexpr int NBM   = (NN + 63) / 64;    // 157
    constexpr int NGEMM = NBM * NTILE;       // 628 or 314
    constexpr int TOTAL = NAGG + NGEMM + NAGG;

    __shared__ ushort Asl[64 * 32];    // 4 KB
    __shared__ ushort Bsl[128 * 32];   // 8 KB
    __shared__ int item_s;

    const int tid  = threadIdx.x;
    const int w    = tid >> 6;
    const int lane = tid & 63;

    for (;;) {
        if (tid == 0) item_s = atomicAdd(queue, 1);
        __syncthreads();
        const int it = item_s;
        if (it >= TOTAL) return;

        if (it < NAGG) {
            // ---------------- agg item: nodes it*4 .. it*4+3 ----------------
            int node = it * 4 + w;
            if (node < n) {
                int start = offsets[node];
                int cnt   = counts[node];
                float inv = inv_cnt[node];
                const uint* xr = (const uint*)xcat + 256;   // right half
                int l4 = lane * 4;
                float acc[8];
#pragma unroll
                for (int k = 0; k < 8; k++) acc[k] = 0.f;
#define ACC8(v) do { \
    acc[0] += blo(v.x); acc[1] += bhi(v.x); \
    acc[2] += blo(v.y); acc[3] += bhi(v.y); \
    acc[4] += blo(v.z); acc[5] += bhi(v.z); \
    acc[6] += blo(v.w); acc[7] += bhi(v.w); } while (0)
                int e = 0;
                for (; e + 4 <= cnt; e += 4) {
                    int s0 = sorted_src[start + e + 0];
                    int s1 = sorted_src[start + e + 1];
                    int s2 = sorted_src[start + e + 2];
                    int s3 = sorted_src[start + e + 3];
                    uint4 v0 = *(const uint4*)(xr + (size_t)s0 * 512 + l4);
                    uint4 v1 = *(const uint4*)(xr + (size_t)s1 * 512 + l4);
                    uint4 v2 = *(const uint4*)(xr + (size_t)s2 * 512 + l4);
                    uint4 v3 = *(const uint4*)(xr + (size_t)s3 * 512 + l4);
                    ACC8(v0); ACC8(v1); ACC8(v2); ACC8(v3);
                }
                for (; e < cnt; e++) {
                    int s0 = sorted_src[start + e];
                    uint4 v0 = *(const uint4*)(xr + (size_t)s0 * 512 + l4);
                    ACC8(v0);
                }
#undef ACC8
                uint4 o;
                o.x = packbf(acc[0] * inv, acc[1] * inv);
                o.y = packbf(acc[2] * inv, acc[3] * inv);
                o.z = packbf(acc[4] * inv, acc[5] * inv);
                o.w = packbf(acc[6] * inv, acc[7] * inv);
                *(uint4*)(xcat + (size_t)node * 1024 + lane * 8) = o;
            }
            __threadfence();
            __syncthreads();
            if (tid == 0) atomicAdd(&aggdone[it >> 4], 1);
        } else if (it < NAGG + NGEMM) {
            // ---------------- gemm tile ----------------
            const int g   = it - NAGG;
            const int bmb = g / NTILE;
            const int bnb = g % NTILE;
            if (tid == 0) {
                int rem = n - bmb * 64;
                int tgt = (rem >= 64) ? 16 : ((rem + 3) >> 2);
                while (atomicAdd(&aggdone[bmb], 0) < tgt)
                    __builtin_amdgcn_s_sleep(8);
            }
            __syncthreads();
            __threadfence();   // acquire: invalidate caches before reading xagg

            const int bm = bmb * 64, bn = bnb * 128;
            const int wm = (w & 1) * 32, wn = (w >> 1) * 64;
            const int row16 = lane & 15, qd = lane >> 4;

            f32x4 acc[2][4];
#pragma unroll
            for (int i = 0; i < 2; i++)
#pragma unroll
                for (int j = 0; j < 4; j++) acc[i][j] = (f32x4){0.f, 0.f, 0.f, 0.f};

            const int sc_r = lane >> 2;
            const int sc_s = lane & 3;
            const int koff = sc_s ^ ((sc_r >> 1) & 3);
            const int swz  = (row16 >> 1) & 3;

            for (int k0 = 0; k0 < 1024; k0 += 32) {
                {
                    int rloc = w * 16 + sc_r;
                    int grow = bm + rloc; grow = grow < n ? grow : n - 1;
                    const ushort* gp = xcat + (size_t)grow * 1024 + k0 + koff * 8;
                    __builtin_amdgcn_global_load_lds(
                        (const __attribute__((address_space(1))) uint32_t*)gp,
                        (__attribute__((address_space(3))) uint32_t*)&Asl[w * 512],
                        16, 0, 0);
                }
#pragma unroll
                for (int c = 0; c < 2; c++) {
                    int chunk = w * 2 + c;
                    int rloc  = chunk * 16 + sc_r;
                    const ushort* gp = B + (size_t)(bn + rloc) * 1024 + k0 + koff * 8;
                    __builtin_amdgcn_global_load_lds(
                        (const __attribute__((address_space(1))) uint32_t*)gp,
                        (__attribute__((address_space(3))) uint32_t*)&Bsl[chunk * 512],
                        16, 0, 0);
                }
                __syncthreads();

                short8 af[2], bfr[4];
                int s = qd ^ swz;
#pragma unroll
                for (int i = 0; i < 2; i++) {
                    int r = wm + i * 16 + row16;
                    af[i] = *(const short8*)&Asl[r * 32 + s * 8];
                }
#pragma unroll
                for (int j = 0; j < 4; j++) {
                    int rn = wn + j * 16 + row16;
                    bfr[j] = *(const short8*)&Bsl[rn * 32 + s * 8];
                }
#pragma unroll
                for (int i = 0; i < 2; i++)
#pragma unroll
                    for (int j = 0; j < 4; j++)
                        acc[i][j] = __builtin_amdgcn_mfma_f32_16x16x32_bf16(
                            af[i], bfr[j], acc[i][j], 0, 0, 0);
                __syncthreads();
            }

            // C/D layout: col = lane&15, row = (lane>>4)*4 + reg  [m89-verified]
#pragma unroll
            for (int i = 0; i < 2; i++) {
#pragma unroll
                for (int r2 = 0; r2 < 4; r2++) {
                    int row = bm + wm + i * 16 + qd * 4 + r2;
                    if (row < n) {
                        float* Cp = Cbuf + (size_t)row * Nn + bn + wn + row16;
#pragma unroll
                        for (int j = 0; j < 4; j++)
                            Cp[j * 16] = acc[i][j][r2];
                    }
                }
            }
            __threadfence();
            __syncthreads();
            if (tid == 0) atomicAdd(&gemmdone[bmb], 1);
        } else {
            // ---------------- finalize item: nodes f*4 .. f*4+3 ----------------
            const int f = it - NAGG - NGEMM;
            if (tid == 0) {
                while (atomicAdd(&gemmdone[f >> 4], 0) < NTILE)
                    __builtin_amdgcn_s_sleep(8);
            }
            __syncthreads();
            __threadfence();   // acquire for Cbuf reads

            constexpr int DOUT = Nn;
            constexpr int PL = DOUT / 64;
            int node = f * 4 + w;
            if (node < n) {
                float v[PL];
                const float* Cp = Cbuf + (size_t)node * DOUT + lane * PL;
                const float* Bp = bias + lane * PL;
#pragma unroll
                for (int k = 0; k < PL; k += 4) {
                    float4 c = *(const float4*)(Cp + k);
                    float4 b = *(const float4*)(Bp + k);
                    v[k + 0] = c.x + b.x; v[k + 1] = c.y + b.y;
                    v[k + 2] = c.z + b.z; v[k + 3] = c.w + b.w;
                }
                float ss = 0.f;
#pragma unroll
                for (int k = 0; k < PL; k++) ss += v[k] * v[k];
#pragma unroll
                for (int m = 32; m >= 1; m >>= 1) ss += __shfl_xor(ss, m, 64);
                float scale = 1.0f / fmaxf(sqrtf(ss), 1e-12f);

                if (FINAL) {
                    float* Op = outf + (size_t)node * DOUT + lane * PL;
#pragma unroll
                    for (int k = 0; k < PL; k += 4) {
                        float4 o;
                        o.x = fmaxf(v[k + 0] * scale, 0.f);
                        o.y = fmaxf(v[k + 1] * scale, 0.f);
                        o.z = fmaxf(v[k + 2] * scale, 0.f);
                        o.w = fmaxf(v[k + 3] * scale, 0.f);
                        *(float4*)(Op + k) = o;
                    }
                } else {
                    uint4 o;
                    float r0 = fmaxf(v[0] * scale, 0.f), r1 = fmaxf(v[1] * scale, 0.f);
                    float r2 = fmaxf(v[2] * scale, 0.f), r3 = fmaxf(v[3] * scale, 0.f);
                    float r4 = fmaxf(v[4] * scale, 0.f), r5 = fmaxf(v[5] * scale, 0.f);
                    float r6 = fmaxf(v[6] * scale, 0.f), r7 = fmaxf(v[7] * scale, 0.f);
                    o.x = packbf(r0, r1); o.y = packbf(r2, r3);
                    o.z = packbf(r4, r5); o.w = packbf(r6, r7);
                    *(uint4*)(xcat + (size_t)node * 1024 + 512 + lane * 8) = o;
                }
            }
        }
        __syncthreads();   // protect item_s before next grab
    }
}

// ---------------------------------------------------------------------------
extern "C" void kernel_launch(void* const* d_in, const int* in_sizes, int n_in,
                              void* d_out, int out_size, void* d_ws, size_t ws_size,
                              hipStream_t stream) {
    const float* x    = (const float*)d_in[0];
    const int*   edge = (const int*)d_in[1];     // [2, E]: src row then dst row
    const float* Wl0  = (const float*)d_in[2];
    const float* b0   = (const float*)d_in[3];
    const float* Wr0  = (const float*)d_in[4];
    const float* Wl1  = (const float*)d_in[5];
    const float* b1   = (const float*)d_in[6];
    const float* Wr1  = (const float*)d_in[7];
    const float* Wl2  = (const float*)d_in[8];
    const float* b2   = (const float*)d_in[9];
    const float* Wr2  = (const float*)d_in[10];

    const int E = in_sizes[1] / 2;

    // Workspace layout (bytes)
    char* ws = (char*)d_ws;
    int*    counts  = (int*)(ws + 0);              // 40000
    int*    offsets = (int*)(ws + 40960);
    int*    cursor  = (int*)(ws + 81920);
    float*  invc    = (float*)(ws + 122880);
    int*    sorted  = (int*)(ws + 163840);         // 640000
    ushort* Wcat    = (ushort*)(ws + 804864);      // 1280*1024*2 = 2621440
    ushort* xcat    = (ushort*)(ws + 3426304);     // 10000*1024*2 = 20480000
    float*  Cbuf    = (float*)(ws + 23906304);     // 10000*512*4  = 20480000
    int*    flagbase= (int*)(ws + 44386304);       // 968 ints (queues+flags)
    // end: 44390176 bytes

    ushort* Wc0 = Wcat;
    ushort* Wc1 = Wcat + 512 * 1024;
    ushort* Wc2 = Wcat + 1024 * 1024;

    // flag layout: [0..3) queues; [8..488) aggdone (160/layer); [488..968) gemmdone
    int* q0 = flagbase + 0;
    int* q1 = flagbase + 1;
    int* q2 = flagbase + 2;
    int* ad0 = flagbase + 8,   * ad1 = flagbase + 168, * ad2 = flagbase + 328;
    int* gd0 = flagbase + 488, * gd1 = flagbase + 648, * gd2 = flagbase + 808;

    // ---- conversions + CSR build (zero/count folded into cvt kernels) ----
    cvt_x<<<(NN * 512 / 4 + 255) / 256, 256, 0, stream>>>(x, xcat, counts, flagbase,
                                                          NN * 512 / 4);
    cvt_w_all<<<(1280 * 1024 / 4 + 255) / 256, 256, 0, stream>>>(
        Wl0, Wr0, Wl1, Wr1, Wl2, Wr2, Wcat, edge + E, counts, E, 1280 * 1024 / 4);
    scan_build<<<1, 1024, 0, stream>>>(counts, offsets, cursor, invc, NN);
    scatter_edges<<<(E + 255) / 256, 256, 0, stream>>>(edge, edge + E, cursor, sorted, E);

    const int PERSIST = 1024;   // persistent blocks; queue handles any residency

    // ---- layer 0 ----
    layer_fused<4, false><<<PERSIST, 256, 0, stream>>>(
        xcat, Wc0, b0, Cbuf, offsets, counts, sorted, invc, q0, ad0, gd0, nullptr, NN);
    // ---- layer 1 ----
    layer_fused<4, false><<<PERSIST, 256, 0, stream>>>(
        xcat, Wc1, b1, Cbuf, offsets, counts, sorted, invc, q1, ad1, gd1, nullptr, NN);
    // ---- layer 2 ----
    layer_fused<2, true><<<PERSIST, 256, 0, stream>>>(
        xcat, Wc2, b2, Cbuf, offsets, counts, sorted, invc, q2, ad2, gd2,
        (float*)d_out, NN);
}